// Round 2
// baseline (4106.242 us; speedup 1.0000x reference)
//
#include <hip/hip_runtime.h>
#include <cstdint>
#include <cstddef>

// ============================================================================
// MixtureOfDepthTransformer on MI355X (gfx950)
// fp16 MFMA GEMMs (fp32 accumulate), fp32 softmax/LN/residual/router.
// All kernels bitwise-deterministic (graph replay must match first call).
// ============================================================================

#define DEV_INLINE __device__ __forceinline__

typedef _Float16 half_t;
typedef half_t half8 __attribute__((ext_vector_type(8)));
typedef float f32x4 __attribute__((ext_vector_type(4)));

DEV_INLINE f32x4 mfma16(half8 a, half8 b, f32x4 c) {
    return __builtin_amdgcn_mfma_f32_16x16x32_f16(a, b, c, 0, 0, 0);
}

DEV_INLINE void cvt8(const float4& a, const float4& b, half8& h) {
    h[0] = (half_t)a.x; h[1] = (half_t)a.y; h[2] = (half_t)a.z; h[3] = (half_t)a.w;
    h[4] = (half_t)b.x; h[5] = (half_t)b.y; h[6] = (half_t)b.z; h[7] = (half_t)b.w;
}

// ---------------------------------------------------------------------------
// fp32 -> fp16 conversion (8 elems / thread)
// ---------------------------------------------------------------------------
__global__ __launch_bounds__(256) void cvt_half8_kernel(
    const float* __restrict__ in, half_t* __restrict__ out, int n8) {
    int i = blockIdx.x * 256 + threadIdx.x;
    if (i >= n8) return;
    const float4* s = (const float4*)in + (size_t)i * 2;
    float4 a = s[0], b = s[1];
    half8 h;
    cvt8(a, b, h);
    ((half8*)out)[i] = h;
}

// ---------------------------------------------------------------------------
// GEMM: C[M,N] = A[M,K] * Bw[N,K]^T + bias, A fp32 or fp16, out fp32/fp16,
// optional ReLU.  128x128x32 tile, 256 thr = 4 waves in 2x2, each wave 64x64
// via 4x4 of mfma_f32_16x16x32_f16.  LDS row stride 40 halfs (80B) to spread
// banks for ds_read_b128.  M,N multiples of 128; K multiple of 32.
// A-frag:  A[m=lane&15][k=(lane>>4)*8+j]
// C/D:     col=lane&15, row=(lane>>4)*4+reg
// ---------------------------------------------------------------------------
template <typename AT, typename OT, bool RELU>
__global__ __launch_bounds__(256)
void gemm_bt(const AT* __restrict__ A, const half_t* __restrict__ Bw,
             const float* __restrict__ bias, OT* __restrict__ C,
             int M, int N, int K) {
    constexpr int LP = 40;
    __shared__ half_t As[128 * LP];
    __shared__ half_t Bs[128 * LP];
    const int tid  = threadIdx.x;
    const int bm = blockIdx.x, bn = blockIdx.y;
    const int lane = tid & 63;
    const int wave = tid >> 6;
    const int wm = (wave >> 1) * 64;
    const int wn = (wave & 1) * 64;
    const int lr = lane & 15;
    const int lq = lane >> 4;
    const int lk = lq * 8;

    const int sr = tid >> 1;           // 0..127: tile row staged by this thread
    const int sc = (tid & 1) * 16;     // col chunk 0 / 16
    const AT*     aglb = A  + (size_t)(bm * 128 + sr) * K + sc;
    const half_t* bglb = Bw + (size_t)(bn * 128 + sr) * K + sc;
    half_t* adst = &As[sr * LP + sc];
    half_t* bdst = &Bs[sr * LP + sc];

    f32x4 acc[4][4] = {};

    for (int k0 = 0; k0 < K; k0 += 32) {
        __syncthreads();
        if constexpr (sizeof(AT) == 4) {
            const float4* s = (const float4*)(aglb + k0);
            float4 v0 = s[0], v1 = s[1], v2 = s[2], v3 = s[3];
            half8 h0, h1;
            cvt8(v0, v1, h0);
            cvt8(v2, v3, h1);
            *(half8*)adst = h0;
            *(half8*)(adst + 8) = h1;
        } else {
            const half8* s = (const half8*)(aglb + k0);
            half8 v0 = s[0], v1 = s[1];
            *(half8*)adst = v0;
            *(half8*)(adst + 8) = v1;
        }
        {
            const half8* s = (const half8*)(bglb + k0);
            half8 v0 = s[0], v1 = s[1];
            *(half8*)bdst = v0;
            *(half8*)(bdst + 8) = v1;
        }
        __syncthreads();
        half8 af[4], bf[4];
#pragma unroll
        for (int i = 0; i < 4; i++)
            af[i] = *(const half8*)&As[(wm + i * 16 + lr) * LP + lk];
#pragma unroll
        for (int j = 0; j < 4; j++)
            bf[j] = *(const half8*)&Bs[(wn + j * 16 + lr) * LP + lk];
#pragma unroll
        for (int i = 0; i < 4; i++)
#pragma unroll
            for (int j = 0; j < 4; j++)
                acc[i][j] = mfma16(af[i], bf[j], acc[i][j]);
    }

#pragma unroll
    for (int i = 0; i < 4; i++) {
#pragma unroll
        for (int j = 0; j < 4; j++) {
            const int col = bn * 128 + wn + j * 16 + lr;
            const float bv = bias[col];
#pragma unroll
            for (int r = 0; r < 4; r++) {
                const int row = bm * 128 + wm + i * 16 + lq * 4 + r;
                float v = acc[i][j][r] + bv;
                if constexpr (RELU) v = fmaxf(v, 0.0f);
                C[(size_t)row * N + col] = (OT)v;
            }
        }
    }
}

// ---------------------------------------------------------------------------
// Flash-style attention.  qkv: [B*T, 3072] fp16 (q|k|v each 1024, head h at
// cols h*64..h*64+63).  o: [B*T, 1024] fp16.
// grid: (T/64, B*H), block 256 = 4 waves; each block does 64 q-rows of (b,h),
// online softmax over key blocks of 64.  P round-trips through LDS to convert
// MFMA C-layout -> A-operand layout.
// ---------------------------------------------------------------------------
__global__ __launch_bounds__(256)
void attn_kernel(const half_t* __restrict__ qkv, half_t* __restrict__ o, int T) {
    const int qb = blockIdx.x;
    const int b  = blockIdx.y >> 4;
    const int h  = blockIdx.y & 15;
    const int tid = threadIdx.x;
    const int wave = tid >> 6, lane = tid & 63;
    const int lr = lane & 15, lq = lane >> 4, lk = lq * 8;

    __shared__ half_t Qs[64][72];
    __shared__ half_t Ks[64][72];
    __shared__ half_t VT[64][72];   // V transposed: VT[d][key]
    __shared__ half_t Ps[64][72];
    __shared__ float  Ss[64][65];
    __shared__ float  m_sh[64], l_sh[64], al_sh[64];

    const half_t* base = qkv + (size_t)(b * T) * 3072 + h * 64;

    {   // load Q tile [64 x 64]
        const int r = tid >> 2, c = (tid & 3) * 16;
        const half_t* src = base + (size_t)(qb * 64 + r) * 3072 + c;
        *(half8*)&Qs[r][c]     = *(const half8*)src;
        *(half8*)&Qs[r][c + 8] = *(const half8*)(src + 8);
    }
    if (tid < 64) { m_sh[tid] = -1e30f; l_sh[tid] = 0.0f; }

    f32x4 oacc[4] = {};

    const int nkb = T >> 6;
    for (int kb = 0; kb < nkb; kb++) {
        __syncthreads();   // previous iter's PV done before K/VT overwrite
        {
            const int r = tid >> 2, c = (tid & 3) * 16;
            const half_t* ks = base + 1024 + (size_t)(kb * 64 + r) * 3072 + c;
            *(half8*)&Ks[r][c]     = *(const half8*)ks;
            *(half8*)&Ks[r][c + 8] = *(const half8*)(ks + 8);
            const half_t* vs = base + 2048 + (size_t)(kb * 64 + r) * 3072 + c;
            half8 v0 = *(const half8*)vs;
            half8 v1 = *(const half8*)(vs + 8);
#pragma unroll
            for (int i = 0; i < 8; i++) VT[c + i][r] = v0[i];
#pragma unroll
            for (int i = 0; i < 8; i++) VT[c + 8 + i][r] = v1[i];
        }
        __syncthreads();
        // S = Q K^T : wave owns q-rows wave*16..+15, all 64 key cols
        f32x4 sacc[4] = {};
#pragma unroll
        for (int kt = 0; kt < 2; kt++) {
            half8 aq = *(const half8*)&Qs[wave * 16 + lr][kt * 32 + lk];
#pragma unroll
            for (int j = 0; j < 4; j++) {
                half8 bk = *(const half8*)&Ks[j * 16 + lr][kt * 32 + lk];
                sacc[j] = mfma16(aq, bk, sacc[j]);
            }
        }
#pragma unroll
        for (int j = 0; j < 4; j++)
#pragma unroll
            for (int r = 0; r < 4; r++)
                Ss[wave * 16 + lq * 4 + r][j * 16 + lr] = sacc[j][r] * 0.125f;
        __syncthreads();
        // online softmax, one thread per q-row
        if (tid < 64) {
            const int row = tid;
            const float m_old = m_sh[row];
            float mx = m_old;
            for (int c = 0; c < 64; c++) mx = fmaxf(mx, Ss[row][c]);
            const float alpha = __expf(m_old - mx);   // first iter: exp(-1e30)=0
            float sum = 0.0f;
            for (int c = 0; c < 64; c++) {
                float pv = __expf(Ss[row][c] - mx);
                sum += pv;
                Ps[row][c] = (half_t)pv;
            }
            m_sh[row] = mx;
            l_sh[row] = l_sh[row] * alpha + sum;
            al_sh[row] = alpha;
        }
        __syncthreads();
        // rescale O, then O += P V
        {
            const float a0 = al_sh[wave * 16 + lq * 4 + 0];
            const float a1 = al_sh[wave * 16 + lq * 4 + 1];
            const float a2 = al_sh[wave * 16 + lq * 4 + 2];
            const float a3 = al_sh[wave * 16 + lq * 4 + 3];
#pragma unroll
            for (int j = 0; j < 4; j++) {
                oacc[j][0] *= a0; oacc[j][1] *= a1;
                oacc[j][2] *= a2; oacc[j][3] *= a3;
            }
        }
#pragma unroll
        for (int kt = 0; kt < 2; kt++) {
            half8 ap = *(const half8*)&Ps[wave * 16 + lr][kt * 32 + lk];
#pragma unroll
            for (int j = 0; j < 4; j++) {
                half8 bv = *(const half8*)&VT[j * 16 + lr][kt * 32 + lk];
                oacc[j] = mfma16(ap, bv, oacc[j]);
            }
        }
    }
    // epilogue: O /= l, write to o[token, h*64 + d]
    half_t* obase = o + (size_t)(b * T + qb * 64) * 1024 + h * 64;
#pragma unroll
    for (int j = 0; j < 4; j++) {
#pragma unroll
        for (int r = 0; r < 4; r++) {
            const int row = wave * 16 + lq * 4 + r;
            float v = oacc[j][r] / l_sh[row];
            obase[(size_t)row * 1024 + j * 16 + lr] = (half_t)v;
        }
    }
}

// ---------------------------------------------------------------------------
// out = LayerNorm(x + r) * g + b   (one block per token, D=1024)
// ---------------------------------------------------------------------------
__global__ __launch_bounds__(256)
void add_ln_kernel(const float* __restrict__ x, const float* __restrict__ r,
                   const float* __restrict__ g, const float* __restrict__ bb,
                   float* __restrict__ out) {
    __shared__ float sh[4];
    const int t = blockIdx.x;
    const int tid = threadIdx.x;
    const float* xr = x + (size_t)t * 1024;
    const float* rr = r + (size_t)t * 1024;
    float v[4];
    float s = 0.0f;
#pragma unroll
    for (int i = 0; i < 4; i++) {
        const int c = tid + i * 256;
        v[i] = xr[c] + rr[c];
        s += v[i];
    }
#pragma unroll
    for (int off = 32; off; off >>= 1) s += __shfl_xor(s, off);
    if ((tid & 63) == 0) sh[tid >> 6] = s;
    __syncthreads();
    const float mean = (sh[0] + sh[1] + sh[2] + sh[3]) * (1.0f / 1024.0f);
    __syncthreads();
    float s2 = 0.0f;
#pragma unroll
    for (int i = 0; i < 4; i++) { const float d = v[i] - mean; s2 += d * d; }
#pragma unroll
    for (int off = 32; off; off >>= 1) s2 += __shfl_xor(s2, off);
    if ((tid & 63) == 0) sh[tid >> 6] = s2;
    __syncthreads();
    const float var = (sh[0] + sh[1] + sh[2] + sh[3]) * (1.0f / 1024.0f);
    const float inv = rsqrtf(var + 1e-5f);
    float* orow = out + (size_t)t * 1024;
#pragma unroll
    for (int i = 0; i < 4; i++) {
        const int c = tid + i * 256;
        orow[c] = (v[i] - mean) * inv * g[c] + bb[c];
    }
}

// ---------------------------------------------------------------------------
// router scores: scores[n] = dot(x[n,:], rw) fp32, one wave per token
// ---------------------------------------------------------------------------
__global__ __launch_bounds__(256)
void router_scores(const float* __restrict__ x, const float* __restrict__ rw,
                   float* __restrict__ scores, int NT) {
    const int w = blockIdx.x * 4 + (threadIdx.x >> 6);
    const int lane = threadIdx.x & 63;
    if (w >= NT) return;
    const float* xr = x + (size_t)w * 1024;
    float s = 0.0f;
    for (int i = lane; i < 1024; i += 64) s += xr[i] * rw[i];
#pragma unroll
    for (int off = 32; off; off >>= 1) s += __shfl_xor(s, off);
    if (lane == 0) scores[w] = s;
}

// ---------------------------------------------------------------------------
// top-1024 of 2048 per batch row via 32-bit radix select on monotone key.
// DETERMINISTIC compaction: scan-based, ascending token order (keys > prefix
// first, then lowest-index ties) — graph replay must be bitwise identical.
// one block per batch row.
// ---------------------------------------------------------------------------
__global__ __launch_bounds__(256)
void topk_select(const float* __restrict__ scores, int* __restrict__ idx,
                 float* __restrict__ wsel) {
    __shared__ unsigned keys[2048];
    __shared__ int cnt;
    __shared__ int wsum_gt[4], wsum_eq[4];
    const int b = blockIdx.x;
    const int tid = threadIdx.x;
    const int lane = tid & 63, wv = tid >> 6;
    const float* s = scores + b * 2048;
    for (int t = tid; t < 2048; t += 256) {
        unsigned u = __float_as_uint(s[t]);
        keys[t] = (u & 0x80000000u) ? ~u : (u | 0x80000000u);
    }
    if (tid == 0) cnt = 0;
    __syncthreads();
    unsigned prefix = 0;
    int remaining = 1024;
    for (int bit = 31; bit >= 0; --bit) {
        const unsigned test = (prefix >> bit) | 1u;
        int local = 0;
        for (int t = tid; t < 2048; t += 256)
            if ((keys[t] >> bit) == test) local++;
        atomicAdd(&cnt, local);   // integer sum: exact, order-independent
        __syncthreads();
        const int c = cnt;
        __syncthreads();
        if (tid == 0) cnt = 0;
        if (c >= remaining) prefix |= (1u << bit);
        else remaining -= c;
        __syncthreads();
    }
    // invariant: count(key > prefix) < 1024 <= count(key >= prefix)
    // blocked ownership: thread tid owns tokens [tid*8, tid*8+8)
    const int base = tid * 8;
    int lgt = 0, leq = 0;
#pragma unroll
    for (int i = 0; i < 8; i++) {
        const unsigned k = keys[base + i];
        lgt += (k > prefix);
        leq += (k == prefix);
    }
    // inclusive scan within wave (width 64), then cross-wave via LDS
    int igt = lgt, ieq = leq;
#pragma unroll
    for (int off = 1; off < 64; off <<= 1) {
        const int ng = __shfl_up(igt, off);
        const int ne = __shfl_up(ieq, off);
        if (lane >= off) { igt += ng; ieq += ne; }
    }
    if (lane == 63) { wsum_gt[wv] = igt; wsum_eq[wv] = ieq; }
    __syncthreads();
    int goff = 0, eoff = 0;
    for (int w = 0; w < wv; w++) { goff += wsum_gt[w]; eoff += wsum_eq[w]; }
    const int n_gt = wsum_gt[0] + wsum_gt[1] + wsum_gt[2] + wsum_gt[3];
    const int need = 1024 - n_gt;          // >= 1 by invariant
    int pg = goff + igt - lgt;             // exclusive offsets for this thread
    int pe = eoff + ieq - leq;
#pragma unroll 1
    for (int i = 0; i < 8; i++) {
        const int t = base + i;
        const unsigned k = keys[t];
        if (k > prefix) {
            idx[b * 1024 + pg] = t;
            wsel[b * 1024 + pg] = 1.0f / (1.0f + __expf(-s[t]));
            pg++;
        } else if (k == prefix) {
            if (pe < need) {
                const int p = n_gt + pe;
                idx[b * 1024 + p] = t;
                wsel[b * 1024 + p] = 1.0f / (1.0f + __expf(-s[t]));
            }
            pe++;
        }
    }
}

// ---------------------------------------------------------------------------
// gather / scatter for MoD (1024-wide rows, one block per selected token)
// ---------------------------------------------------------------------------
__global__ __launch_bounds__(256)
void gather_kernel(const float* __restrict__ x, const int* __restrict__ idx,
                   float* __restrict__ sel) {
    const int j = blockIdx.x;
    const int b = j >> 10;
    const int tok = idx[j];
    const float4* src = (const float4*)(x + (size_t)(b * 2048 + tok) * 1024);
    float4* dst = (float4*)(sel + (size_t)j * 1024);
    dst[threadIdx.x] = src[threadIdx.x];
}

__global__ __launch_bounds__(256)
void scatter_kernel(float* __restrict__ x, const float* __restrict__ sel,
                    const float* __restrict__ proc, const int* __restrict__ idx,
                    const float* __restrict__ w) {
    const int j = blockIdx.x;
    const int b = j >> 10;
    const int tok = idx[j];
    const float wt = w[j];
    float4* dst = (float4*)(x + (size_t)(b * 2048 + tok) * 1024);
    const float4* sp = (const float4*)(sel + (size_t)j * 1024);
    const float4* pp = (const float4*)(proc + (size_t)j * 1024);
    float4 d = dst[threadIdx.x], s = sp[threadIdx.x], p = pp[threadIdx.x];
    d.x += (p.x - s.x) * wt;
    d.y += (p.y - s.y) * wt;
    d.z += (p.z - s.z) * wt;
    d.w += (p.w - s.w) * wt;
    dst[threadIdx.x] = d;
}

// ---------------------------------------------------------------------------
// host-side encoder-layer driver
// ---------------------------------------------------------------------------
struct EncCtx {
    const float *bqkv, *bo, *b1, *b2, *g1, *be1, *g2, *be2;
    const half_t *Wqkv_h, *Wo_h, *W1_h, *W2_h;
    half_t *qkv_h, *o_h, *h_h;
    float *tmp_f, *y_f;
};

static void run_encoder(const EncCtx& c, int layer, const float* xin, float* xout,
                        int N, int T, hipStream_t stream) {
    const half_t* Wq = c.Wqkv_h + (size_t)layer * 3072 * 1024;
    const half_t* Wo = c.Wo_h   + (size_t)layer * 1024 * 1024;
    const half_t* W1 = c.W1_h   + (size_t)layer * 4096 * 1024;
    const half_t* W2 = c.W2_h   + (size_t)layer * 1024 * 4096;
    // qkv = x Wqkv^T + bqkv  -> fp16
    gemm_bt<float, half_t, false><<<dim3(N / 128, 24), 256, 0, stream>>>(
        xin, Wq, c.bqkv + layer * 3072, c.qkv_h, N, 3072, 1024);
    // attention
    attn_kernel<<<dim3(T / 64, (N / T) * 16), 256, 0, stream>>>(c.qkv_h, c.o_h, T);
    // attnout = o Wo^T + bo  -> fp32
    gemm_bt<half_t, float, false><<<dim3(N / 128, 8), 256, 0, stream>>>(
        c.o_h, Wo, c.bo + layer * 1024, c.tmp_f, N, 1024, 1024);
    // y = LN(x + attnout)
    add_ln_kernel<<<N, 256, 0, stream>>>(xin, c.tmp_f, c.g1 + layer * 1024,
                                         c.be1 + layer * 1024, c.y_f);
    // h = relu(y W1^T + b1)  -> fp16
    gemm_bt<float, half_t, true><<<dim3(N / 128, 32), 256, 0, stream>>>(
        c.y_f, W1, c.b1 + layer * 4096, c.h_h, N, 4096, 1024);
    // f = h W2^T + b2  -> fp32 (reuse tmp_f)
    gemm_bt<half_t, float, false><<<dim3(N / 128, 8), 256, 0, stream>>>(
        c.h_h, W2, c.b2 + layer * 1024, c.tmp_f, N, 1024, 4096);
    // xout = LN(y + f)
    add_ln_kernel<<<N, 256, 0, stream>>>(c.y_f, c.tmp_f, c.g2 + layer * 1024,
                                         c.be2 + layer * 1024, xout);
}

// ---------------------------------------------------------------------------
extern "C" void kernel_launch(void* const* d_in, const int* in_sizes, int n_in,
                              void* d_out, int out_size, void* d_ws, size_t ws_size,
                              hipStream_t stream) {
    (void)in_sizes; (void)n_in; (void)ws_size;
    const float* X    = (const float*)d_in[0];
    const float* Wqkv = (const float*)d_in[1];
    const float* bqkv = (const float*)d_in[2];
    const float* Wo   = (const float*)d_in[3];
    const float* bo   = (const float*)d_in[4];
    const float* W1   = (const float*)d_in[5];
    const float* b1   = (const float*)d_in[6];
    const float* W2   = (const float*)d_in[7];
    const float* b2   = (const float*)d_in[8];
    const float* g1   = (const float*)d_in[9];
    const float* be1  = (const float*)d_in[10];
    const float* g2   = (const float*)d_in[11];
    const float* be2  = (const float*)d_in[12];
    const float* rw   = (const float*)d_in[13];

    float* x = (float*)d_out;  // work in-place on the output buffer
    hipMemcpyAsync(x, X, (size_t)out_size * sizeof(float),
                   hipMemcpyDeviceToDevice, stream);

    // ---- workspace carve (~386 MB) ----
    char* p = (char*)d_ws;
    auto carve = [&](size_t bytes) -> char* {
        char* r = p;
        p += (bytes + 255) & ~(size_t)255;
        return r;
    };
    const size_t nWqkv = 6ull * 3072 * 1024;
    const size_t nWo   = 6ull * 1024 * 1024;
    const size_t nW1   = 6ull * 4096 * 1024;
    const size_t nW2   = 6ull * 1024 * 4096;
    half_t* Wqkv_h = (half_t*)carve(nWqkv * 2);
    half_t* Wo_h   = (half_t*)carve(nWo * 2);
    half_t* W1_h   = (half_t*)carve(nW1 * 2);
    half_t* W2_h   = (half_t*)carve(nW2 * 2);
    half_t* qkv_h  = (half_t*)carve(8192ull * 3072 * 2);
    half_t* o_h    = (half_t*)carve(8192ull * 1024 * 2);
    half_t* h_h    = (half_t*)carve(8192ull * 4096 * 2);
    float*  tmp_f  = (float*)carve(8192ull * 1024 * 4);
    float*  y_f    = (float*)carve(8192ull * 1024 * 4);
    float*  sel_f  = (float*)carve(4096ull * 1024 * 4);
    float*  proc_f = (float*)carve(4096ull * 1024 * 4);
    float*  scores = (float*)carve(8192ull * 4);
    int*    idx    = (int*)carve(4096ull * 4);
    float*  wsel   = (float*)carve(4096ull * 4);

    // ---- weights fp32 -> fp16 (per call: ws is re-poisoned each launch) ----
    auto cvt = [&](const float* src, half_t* dst, size_t n) {
        const int n8 = (int)(n / 8);
        cvt_half8_kernel<<<(n8 + 255) / 256, 256, 0, stream>>>(src, dst, n8);
    };
    cvt(Wqkv, Wqkv_h, nWqkv);
    cvt(Wo, Wo_h, nWo);
    cvt(W1, W1_h, nW1);
    cvt(W2, W2_h, nW2);

    EncCtx c{bqkv, bo, b1, b2, g1, be1, g2, be2,
             Wqkv_h, Wo_h, W1_h, W2_h, qkv_h, o_h, h_h, tmp_f, y_f};

    for (int layer = 0; layer < 6; layer++) {
        if (layer & 1) {
            // MoD: route top-1024 of 2048 tokens per sequence
            router_scores<<<2048, 256, 0, stream>>>(x, rw + layer * 1024, scores, 8192);
            topk_select<<<4, 256, 0, stream>>>(scores, idx, wsel);
            gather_kernel<<<4096, 256, 0, stream>>>(x, idx, sel_f);
            run_encoder(c, layer, sel_f, proc_f, 4096, 1024, stream);
            scatter_kernel<<<4096, 256, 0, stream>>>(x, sel_f, proc_f, idx, wsel);
        } else {
            run_encoder(c, layer, x, x, 8192, 2048, stream);
        }
    }
}

// Round 4
// 3427.949 us; speedup vs baseline: 1.1979x; 1.1979x over previous
//
#include <hip/hip_runtime.h>
#include <cstdint>
#include <cstddef>

// ============================================================================
// MixtureOfDepthTransformer on MI355X (gfx950)
// fp16 MFMA GEMMs (fp32 accumulate), fp32 softmax/LN/residual/router.
// R4: fix global_load_lds LDS pointer to be wave-uniform (readfirstlane);
// workspace aliased down to ~361 MB. All kernels bitwise-deterministic.
// ============================================================================

#define DEV_INLINE __device__ __forceinline__

typedef _Float16 half_t;
typedef half_t half8 __attribute__((ext_vector_type(8)));
typedef half_t half4 __attribute__((ext_vector_type(4)));
typedef float f32x4 __attribute__((ext_vector_type(4)));

DEV_INLINE f32x4 mfma16(half8 a, half8 b, f32x4 c) {
    return __builtin_amdgcn_mfma_f32_16x16x32_f16(a, b, c, 0, 0, 0);
}

DEV_INLINE void cvt8(const float4& a, const float4& b, half8& h) {
    h[0] = (half_t)a.x; h[1] = (half_t)a.y; h[2] = (half_t)a.z; h[3] = (half_t)a.w;
    h[4] = (half_t)b.x; h[5] = (half_t)b.y; h[6] = (half_t)b.z; h[7] = (half_t)b.w;
}

// async global->LDS, 16B per lane. lptr MUST be wave-uniform; HW writes each
// lane's 16B at lptr + lane*16.
DEV_INLINE void lds_load16(const half_t* g, half_t* l) {
    __builtin_amdgcn_global_load_lds(
        (const __attribute__((address_space(1))) void*)g,
        (__attribute__((address_space(3))) void*)l, 16, 0, 0);
}

// ---------------------------------------------------------------------------
// fp32 -> fp16 conversion (8 elems / thread)
// ---------------------------------------------------------------------------
__global__ __launch_bounds__(256) void cvt_half8_kernel(
    const float* __restrict__ in, half_t* __restrict__ out, int n8) {
    int i = blockIdx.x * 256 + threadIdx.x;
    if (i >= n8) return;
    const float4* s = (const float4*)in + (size_t)i * 2;
    float4 a = s[0], b = s[1];
    half8 h;
    cvt8(a, b, h);
    ((half8*)out)[i] = h;
}

// ---------------------------------------------------------------------------
// GEMM: C[M,N] = A[M,K] * Bw[N,K]^T + bias; A,B fp16, out fp32/fp16, opt ReLU.
// 128x128x32 tile, 256 thr = 4 waves 2x2, wave does 64x64 via 4x4 mfma 16x16x32.
// Staging via global_load_lds width 16 into UNPADDED LDS (stride 32 halfs).
// Wave w covers LDS bytes [w*1024, w*1024+1024): base is wave-uniform
// (readfirstlane), HW adds lane*16. Lane l of wave w loads global row
// ((w*64+l)>>2), col chunk ((l&3)*8) -> LDS row w*16+(l>>2), col (l&3)*8.
// ---------------------------------------------------------------------------
template <typename OT, bool RELU>
__global__ __launch_bounds__(256)
void gemm_bt(const half_t* __restrict__ A, const half_t* __restrict__ Bw,
             const float* __restrict__ bias, OT* __restrict__ C,
             int N, int K) {
    __shared__ half_t As[128 * 32];
    __shared__ half_t Bs[128 * 32];
    const int tid  = threadIdx.x;
    const int bm = blockIdx.x, bn = blockIdx.y;
    const int lane = tid & 63;
    const int wave = tid >> 6;
    const int wm = (wave >> 1) * 64;
    const int wn = (wave & 1) * 64;
    const int lr = lane & 15;
    const int lq = lane >> 4;
    const int lk = lq * 8;

    // global: thread tid covers rows (tid>>2) and (tid>>2)+64, col (tid&3)*8
    const half_t* aglb = A  + (size_t)(bm * 128 + (tid >> 2)) * K + (tid & 3) * 8;
    const half_t* bglb = Bw + (size_t)(bn * 128 + (tid >> 2)) * K + (tid & 3) * 8;
    const size_t rows64 = 64ull * K;
    // wave-uniform LDS staging base (halfs): wave*512
    const int wbase = __builtin_amdgcn_readfirstlane(tid & 192) * 8;
    half_t* adst = As + wbase;
    half_t* bdst = Bs + wbase;

    f32x4 acc[4][4] = {};

    for (int k0 = 0; k0 < K; k0 += 32) {
        __syncthreads();
        lds_load16(aglb + k0,          adst);
        lds_load16(aglb + k0 + rows64, adst + 2048);
        lds_load16(bglb + k0,          bdst);
        lds_load16(bglb + k0 + rows64, bdst + 2048);
        __syncthreads();   // drains vmcnt(0): staged data visible
        half8 af[4], bf[4];
#pragma unroll
        for (int i = 0; i < 4; i++)
            af[i] = *(const half8*)&As[(wm + i * 16 + lr) * 32 + lk];
#pragma unroll
        for (int j = 0; j < 4; j++)
            bf[j] = *(const half8*)&Bs[(wn + j * 16 + lr) * 32 + lk];
#pragma unroll
        for (int i = 0; i < 4; i++)
#pragma unroll
            for (int j = 0; j < 4; j++)
                acc[i][j] = mfma16(af[i], bf[j], acc[i][j]);
    }

#pragma unroll
    for (int i = 0; i < 4; i++) {
#pragma unroll
        for (int j = 0; j < 4; j++) {
            const int col = bn * 128 + wn + j * 16 + lr;
            const float bv = bias[col];
#pragma unroll
            for (int r = 0; r < 4; r++) {
                const int row = bm * 128 + wm + i * 16 + lq * 4 + r;
                float v = acc[i][j][r] + bv;
                if constexpr (RELU) v = fmaxf(v, 0.0f);
                C[(size_t)row * N + col] = (OT)v;
            }
        }
    }
}

// ---------------------------------------------------------------------------
// V pre-transpose: qkv[N,3072] (V at cols 2048+h*64+d) -> vt[bh][d][t]
// grid (T/64, B*H), 64x64 tile through LDS.
// ---------------------------------------------------------------------------
__global__ __launch_bounds__(256)
void vt_transpose(const half_t* __restrict__ qkv, half_t* __restrict__ vt, int T) {
    const int tb = blockIdx.x, bh = blockIdx.y;
    const int b = bh >> 4, h = bh & 15;
    __shared__ half_t tile[64][72];
    const int tid = threadIdx.x;
    const int r = tid >> 2, c = (tid & 3) * 16;
    const half_t* src = qkv + (size_t)(b * T + tb * 64 + r) * 3072 + 2048 + h * 64 + c;
    *(half8*)&tile[r][c]     = *(const half8*)src;
    *(half8*)&tile[r][c + 8] = *(const half8*)(src + 8);
    __syncthreads();
    const int d = tid >> 2;
    half8 o0, o1;
#pragma unroll
    for (int i = 0; i < 8; i++) o0[i] = tile[c + i][d];
#pragma unroll
    for (int i = 0; i < 8; i++) o1[i] = tile[c + 8 + i][d];
    half_t* dst = vt + ((size_t)bh * 64 + d) * T + tb * 64 + c;
    *(half8*)dst = o0;
    *(half8*)(dst + 8) = o1;
}

// ---------------------------------------------------------------------------
// Flash attention, in-register online softmax.
// qkv: [B*T,3072] fp16; vt: [B*H,64,T] fp16; o: [B*T,1024] fp16.
// grid (T/64, B*H), 256 thr = 4 waves; wave owns 16 q-rows.
// Row state (m,l) replicated across the 16 lanes sharing lq; reductions via
// __shfl_xor over lr group. P round-trips LDS (C-layout -> A-layout), rows
// are wave-private so no extra barrier.
// ---------------------------------------------------------------------------
__global__ __launch_bounds__(256)
void attn_kernel(const half_t* __restrict__ qkv, const half_t* __restrict__ vt,
                 half_t* __restrict__ o, int T) {
    const int qb = blockIdx.x;
    const int bh = blockIdx.y;
    const int b = bh >> 4, h = bh & 15;
    const int tid = threadIdx.x;
    const int wave = tid >> 6, lane = tid & 63;
    const int lr = lane & 15, lq = lane >> 4, lk = lq * 8;

    __shared__ half_t Qs[64][72];
    __shared__ half_t Ks[64][72];
    __shared__ half_t Vs[64][72];   // V^T tile: Vs[d][key]
    __shared__ half_t Ps[64][72];

    const half_t* base = qkv + (size_t)(b * T) * 3072 + h * 64;
    {   // load Q tile [64 tokens x 64 d]
        const int r = tid >> 2, c = (tid & 3) * 16;
        const half_t* src = base + (size_t)(qb * 64 + r) * 3072 + c;
        *(half8*)&Qs[r][c]     = *(const half8*)src;
        *(half8*)&Qs[r][c + 8] = *(const half8*)(src + 8);
    }

    float m_i[4] = {-1e30f, -1e30f, -1e30f, -1e30f};
    float l_i[4] = {0.f, 0.f, 0.f, 0.f};
    f32x4 oacc[4] = {};   // oacc[j][r] = O[wave*16+lq*4+r][j*16+lr]

    const half_t* vbase = vt + (size_t)bh * 64 * T;
    const int nkb = T >> 6;
    for (int kb = 0; kb < nkb; kb++) {
        __syncthreads();   // prev iter's reads of Ks/Vs done
        {   // stage K [64 keys x 64 d] and V^T [64 d x 64 keys]
            const int r = tid >> 2, c = (tid & 3) * 16;
            const half_t* ks = base + 1024 + (size_t)(kb * 64 + r) * 3072 + c;
            *(half8*)&Ks[r][c]     = *(const half8*)ks;
            *(half8*)&Ks[r][c + 8] = *(const half8*)(ks + 8);
            const half_t* vs = vbase + (size_t)r * T + kb * 64 + c;
            *(half8*)&Vs[r][c]     = *(const half8*)vs;
            *(half8*)&Vs[r][c + 8] = *(const half8*)(vs + 8);
        }
        __syncthreads();
        // S = Q K^T (scaled): sacc[j][r] = S[wave*16+lq*4+r][j*16+lr]
        f32x4 sacc[4] = {};
#pragma unroll
        for (int kt = 0; kt < 2; kt++) {
            half8 aq = *(const half8*)&Qs[wave * 16 + lr][kt * 32 + lk];
#pragma unroll
            for (int j = 0; j < 4; j++) {
                half8 bk = *(const half8*)&Ks[j * 16 + lr][kt * 32 + lk];
                sacc[j] = mfma16(aq, bk, sacc[j]);
            }
        }
#pragma unroll
        for (int j = 0; j < 4; j++)
#pragma unroll
            for (int r = 0; r < 4; r++) sacc[j][r] *= 0.125f;
        // in-register online softmax (reduce over the 16-lane lr group)
        float alpha[4];
#pragma unroll
        for (int r = 0; r < 4; r++) {
            float mx = fmaxf(fmaxf(sacc[0][r], sacc[1][r]),
                             fmaxf(sacc[2][r], sacc[3][r]));
#pragma unroll
            for (int off = 1; off < 16; off <<= 1)
                mx = fmaxf(mx, __shfl_xor(mx, off));
            const float mnew = fmaxf(m_i[r], mx);
            alpha[r] = __expf(m_i[r] - mnew);
            m_i[r] = mnew;
            float sum = 0.0f;
#pragma unroll
            for (int j = 0; j < 4; j++) {
                const float pv = __expf(sacc[j][r] - mnew);
                sum += pv;
                Ps[wave * 16 + lq * 4 + r][j * 16 + lr] = (half_t)pv;
            }
#pragma unroll
            for (int off = 1; off < 16; off <<= 1) sum += __shfl_xor(sum, off);
            l_i[r] = l_i[r] * alpha[r] + sum;
        }
        // rescale O, accumulate O += P V
#pragma unroll
        for (int j = 0; j < 4; j++)
#pragma unroll
            for (int r = 0; r < 4; r++) oacc[j][r] *= alpha[r];
#pragma unroll
        for (int kt = 0; kt < 2; kt++) {
            half8 ap = *(const half8*)&Ps[wave * 16 + lr][kt * 32 + lk];
#pragma unroll
            for (int j = 0; j < 4; j++) {
                half8 bv = *(const half8*)&Vs[j * 16 + lr][kt * 32 + lk];
                oacc[j] = mfma16(ap, bv, oacc[j]);
            }
        }
    }
    // epilogue: O /= l, write o[token, h*64+d]
    half_t* obase = o + (size_t)(b * T + qb * 64) * 1024 + h * 64;
#pragma unroll
    for (int j = 0; j < 4; j++) {
#pragma unroll
        for (int r = 0; r < 4; r++) {
            const int row = wave * 16 + lq * 4 + r;
            obase[(size_t)row * 1024 + j * 16 + lr] = (half_t)(oacc[j][r] / l_i[r]);
        }
    }
}

// ---------------------------------------------------------------------------
// out = LayerNorm(x + r) * g + b (fp32), plus fp16 mirror. One block/token.
// ---------------------------------------------------------------------------
__global__ __launch_bounds__(256)
void add_ln_kernel(const float* __restrict__ x, const float* __restrict__ r,
                   const float* __restrict__ g, const float* __restrict__ bb,
                   float* __restrict__ out, half_t* __restrict__ out_h) {
    __shared__ float sh[4];
    const int t = blockIdx.x;
    const int tid = threadIdx.x;
    const float* xr = x + (size_t)t * 1024;
    const float* rr = r + (size_t)t * 1024;
    float v[4];
    float s = 0.0f;
#pragma unroll
    for (int i = 0; i < 4; i++) {
        const int c = tid + i * 256;
        v[i] = xr[c] + rr[c];
        s += v[i];
    }
#pragma unroll
    for (int off = 32; off; off >>= 1) s += __shfl_xor(s, off);
    if ((tid & 63) == 0) sh[tid >> 6] = s;
    __syncthreads();
    const float mean = (sh[0] + sh[1] + sh[2] + sh[3]) * (1.0f / 1024.0f);
    __syncthreads();
    float s2 = 0.0f;
#pragma unroll
    for (int i = 0; i < 4; i++) { const float d = v[i] - mean; s2 += d * d; }
#pragma unroll
    for (int off = 32; off; off >>= 1) s2 += __shfl_xor(s2, off);
    if ((tid & 63) == 0) sh[tid >> 6] = s2;
    __syncthreads();
    const float var = (sh[0] + sh[1] + sh[2] + sh[3]) * (1.0f / 1024.0f);
    const float inv = rsqrtf(var + 1e-5f);
    float* orow = out + (size_t)t * 1024;
    half_t* hrow = out_h + (size_t)t * 1024;
#pragma unroll
    for (int i = 0; i < 4; i++) {
        const int c = tid + i * 256;
        const float y = (v[i] - mean) * inv * g[c] + bb[c];
        orow[c] = y;
        hrow[c] = (half_t)y;
    }
}

// ---------------------------------------------------------------------------
// router scores: scores[n] = dot(x[n,:], rw) fp32, one wave per token
// ---------------------------------------------------------------------------
__global__ __launch_bounds__(256)
void router_scores(const float* __restrict__ x, const float* __restrict__ rw,
                   float* __restrict__ scores, int NT) {
    const int w = blockIdx.x * 4 + (threadIdx.x >> 6);
    const int lane = threadIdx.x & 63;
    if (w >= NT) return;
    const float* xr = x + (size_t)w * 1024;
    float s = 0.0f;
    for (int i = lane; i < 1024; i += 64) s += xr[i] * rw[i];
#pragma unroll
    for (int off = 32; off; off >>= 1) s += __shfl_xor(s, off);
    if (lane == 0) scores[w] = s;
}

// ---------------------------------------------------------------------------
// top-1024 of 2048 per batch row, radix select; deterministic scan compaction.
// ---------------------------------------------------------------------------
__global__ __launch_bounds__(256)
void topk_select(const float* __restrict__ scores, int* __restrict__ idx,
                 float* __restrict__ wsel) {
    __shared__ unsigned keys[2048];
    __shared__ int cnt;
    __shared__ int wsum_gt[4], wsum_eq[4];
    const int b = blockIdx.x;
    const int tid = threadIdx.x;
    const int lane = tid & 63, wv = tid >> 6;
    const float* s = scores + b * 2048;
    for (int t = tid; t < 2048; t += 256) {
        unsigned u = __float_as_uint(s[t]);
        keys[t] = (u & 0x80000000u) ? ~u : (u | 0x80000000u);
    }
    if (tid == 0) cnt = 0;
    __syncthreads();
    unsigned prefix = 0;
    int remaining = 1024;
    for (int bit = 31; bit >= 0; --bit) {
        const unsigned test = (prefix >> bit) | 1u;
        int local = 0;
        for (int t = tid; t < 2048; t += 256)
            if ((keys[t] >> bit) == test) local++;
        atomicAdd(&cnt, local);   // integer sum: exact, order-independent
        __syncthreads();
        const int c = cnt;
        __syncthreads();
        if (tid == 0) cnt = 0;
        if (c >= remaining) prefix |= (1u << bit);
        else remaining -= c;
        __syncthreads();
    }
    const int base = tid * 8;
    int lgt = 0, leq = 0;
#pragma unroll
    for (int i = 0; i < 8; i++) {
        const unsigned k = keys[base + i];
        lgt += (k > prefix);
        leq += (k == prefix);
    }
    int igt = lgt, ieq = leq;
#pragma unroll
    for (int off = 1; off < 64; off <<= 1) {
        const int ng = __shfl_up(igt, off);
        const int ne = __shfl_up(ieq, off);
        if (lane >= off) { igt += ng; ieq += ne; }
    }
    if (lane == 63) { wsum_gt[wv] = igt; wsum_eq[wv] = ieq; }
    __syncthreads();
    int goff = 0, eoff = 0;
    for (int w = 0; w < wv; w++) { goff += wsum_gt[w]; eoff += wsum_eq[w]; }
    const int n_gt = wsum_gt[0] + wsum_gt[1] + wsum_gt[2] + wsum_gt[3];
    const int need = 1024 - n_gt;
    int pg = goff + igt - lgt;
    int pe = eoff + ieq - leq;
#pragma unroll 1
    for (int i = 0; i < 8; i++) {
        const int t = base + i;
        const unsigned k = keys[t];
        if (k > prefix) {
            idx[b * 1024 + pg] = t;
            wsel[b * 1024 + pg] = 1.0f / (1.0f + __expf(-s[t]));
            pg++;
        } else if (k == prefix) {
            if (pe < need) {
                const int p = n_gt + pe;
                idx[b * 1024 + p] = t;
                wsel[b * 1024 + p] = 1.0f / (1.0f + __expf(-s[t]));
            }
            pe++;
        }
    }
}

// ---------------------------------------------------------------------------
// gather / scatter for MoD (fp32 + fp16 mirrors)
// ---------------------------------------------------------------------------
__global__ __launch_bounds__(256)
void gather_kernel(const float* __restrict__ x, const int* __restrict__ idx,
                   float* __restrict__ sel, half_t* __restrict__ sel_h) {
    const int j = blockIdx.x;
    const int b = j >> 10;
    const int tok = idx[j];
    const float4* src = (const float4*)(x + (size_t)(b * 2048 + tok) * 1024);
    float4 v = src[threadIdx.x];
    ((float4*)(sel + (size_t)j * 1024))[threadIdx.x] = v;
    half4 hv; hv[0] = (half_t)v.x; hv[1] = (half_t)v.y;
    hv[2] = (half_t)v.z; hv[3] = (half_t)v.w;
    ((half4*)(sel_h + (size_t)j * 1024))[threadIdx.x] = hv;
}

__global__ __launch_bounds__(256)
void scatter_kernel(float* __restrict__ x, half_t* __restrict__ x_h,
                    const float* __restrict__ sel,
                    const float* __restrict__ proc, const int* __restrict__ idx,
                    const float* __restrict__ w) {
    const int j = blockIdx.x;
    const int b = j >> 10;
    const int tok = idx[j];
    const float wt = w[j];
    float4* dst = (float4*)(x + (size_t)(b * 2048 + tok) * 1024);
    const float4* sp = (const float4*)(sel + (size_t)j * 1024);
    const float4* pp = (const float4*)(proc + (size_t)j * 1024);
    float4 d = dst[threadIdx.x], s = sp[threadIdx.x], p = pp[threadIdx.x];
    d.x += (p.x - s.x) * wt;
    d.y += (p.y - s.y) * wt;
    d.z += (p.z - s.z) * wt;
    d.w += (p.w - s.w) * wt;
    dst[threadIdx.x] = d;
    half4 hv; hv[0] = (half_t)d.x; hv[1] = (half_t)d.y;
    hv[2] = (half_t)d.z; hv[3] = (half_t)d.w;
    ((half4*)(x_h + (size_t)(b * 2048 + tok) * 1024))[threadIdx.x] = hv;
}

// ---------------------------------------------------------------------------
// host-side encoder-layer driver
// ---------------------------------------------------------------------------
struct EncCtx {
    const float *bqkv, *bo, *b1, *b2, *g1, *be1, *g2, *be2;
    const half_t *Wqkv_h, *Wo_h, *W1_h, *W2_h;
    half_t *qkv_h, *o_h, *h_h, *vt, *y_h;
    float *tmp_f, *y_f;
};

static void run_encoder(const EncCtx& c, int layer,
                        const float* xin, const half_t* xin_h,
                        float* xout, half_t* xout_h,
                        int N, int T, hipStream_t stream) {
    const half_t* Wq = c.Wqkv_h + (size_t)layer * 3072 * 1024;
    const half_t* Wo = c.Wo_h   + (size_t)layer * 1024 * 1024;
    const half_t* W1 = c.W1_h   + (size_t)layer * 4096 * 1024;
    const half_t* W2 = c.W2_h   + (size_t)layer * 1024 * 4096;
    const int BH = (N / T) * 16;
    // qkv = x Wqkv^T + bqkv -> fp16   (reads xin_h; writes qkv_h)
    gemm_bt<half_t, false><<<dim3(N / 128, 24), 256, 0, stream>>>(
        xin_h, Wq, c.bqkv + layer * 3072, c.qkv_h, 3072, 1024);
    // V^T
    vt_transpose<<<dim3(T / 64, BH), 256, 0, stream>>>(c.qkv_h, c.vt, T);
    // attention (qkv_h, vt dead after this)
    attn_kernel<<<dim3(T / 64, BH), 256, 0, stream>>>(c.qkv_h, c.vt, c.o_h, T);
    // attnout = o Wo^T + bo -> fp32 (o_h dead after this)
    gemm_bt<float, false><<<dim3(N / 128, 8), 256, 0, stream>>>(
        c.o_h, Wo, c.bo + layer * 1024, c.tmp_f, 1024, 1024);
    // y = LN(x + attnout)   (y_h aliases o_h — safe, o_h dead)
    add_ln_kernel<<<N, 256, 0, stream>>>(xin, c.tmp_f, c.g1 + layer * 1024,
                                         c.be1 + layer * 1024, c.y_f, c.y_h);
    // h = relu(y W1^T + b1) -> fp16  (h_h aliases qkv_h/vt — safe, both dead)
    gemm_bt<half_t, true><<<dim3(N / 128, 32), 256, 0, stream>>>(
        c.y_h, W1, c.b1 + layer * 4096, c.h_h, 4096, 1024);
    // f = h W2^T + b2 -> fp32
    gemm_bt<float, false><<<dim3(N / 128, 8), 256, 0, stream>>>(
        c.h_h, W2, c.b2 + layer * 1024, c.tmp_f, 1024, 4096);
    // xout = LN(y + f)
    add_ln_kernel<<<N, 256, 0, stream>>>(c.y_f, c.tmp_f, c.g2 + layer * 1024,
                                         c.be2 + layer * 1024, xout, xout_h);
}

// ---------------------------------------------------------------------------
extern "C" void kernel_launch(void* const* d_in, const int* in_sizes, int n_in,
                              void* d_out, int out_size, void* d_ws, size_t ws_size,
                              hipStream_t stream) {
    (void)in_sizes; (void)n_in; (void)ws_size;
    const float* X    = (const float*)d_in[0];
    const float* Wqkv = (const float*)d_in[1];
    const float* bqkv = (const float*)d_in[2];
    const float* Wo   = (const float*)d_in[3];
    const float* bo   = (const float*)d_in[4];
    const float* W1   = (const float*)d_in[5];
    const float* b1   = (const float*)d_in[6];
    const float* W2   = (const float*)d_in[7];
    const float* b2   = (const float*)d_in[8];
    const float* g1   = (const float*)d_in[9];
    const float* be1  = (const float*)d_in[10];
    const float* g2   = (const float*)d_in[11];
    const float* be2  = (const float*)d_in[12];
    const float* rw   = (const float*)d_in[13];

    float* x = (float*)d_out;  // fp32 state, in-place in output buffer
    hipMemcpyAsync(x, X, (size_t)out_size * sizeof(float),
                   hipMemcpyDeviceToDevice, stream);

    // ---- workspace carve (~361 MB with liveness aliasing) ----
    char* p = (char*)d_ws;
    auto carve = [&](size_t bytes) -> char* {
        char* r = p;
        p += (bytes + 255) & ~(size_t)255;
        return r;
    };
    const size_t nWqkv = 6ull * 3072 * 1024;
    const size_t nWo   = 6ull * 1024 * 1024;
    const size_t nW1   = 6ull * 4096 * 1024;
    const size_t nW2   = 6ull * 1024 * 4096;
    half_t* Wqkv_h = (half_t*)carve(nWqkv * 2);
    half_t* Wo_h   = (half_t*)carve(nWo * 2);
    half_t* W1_h   = (half_t*)carve(nW1 * 2);
    half_t* W2_h   = (half_t*)carve(nW2 * 2);
    // big0: h_h [8192,4096] overlays qkv_h [8192,3072] ++ vt [BH,64,T]
    half_t* big0   = (half_t*)carve(8192ull * 4096 * 2);
    half_t* qkv_h  = big0;
    half_t* vt     = big0 + 8192ull * 3072;
    half_t* h_h    = big0;
    // big1: o_h / y_h (disjoint lifetimes within a layer)
    half_t* big1   = (half_t*)carve(8192ull * 1024 * 2);
    half_t* o_h    = big1;
    half_t* y_h    = big1;
    half_t* x_h    = (half_t*)carve(8192ull * 1024 * 2);
    half_t* sel_h  = (half_t*)carve(4096ull * 1024 * 2);
    float*  tmp_f  = (float*)carve(8192ull * 1024 * 4);
    float*  y_f    = (float*)carve(8192ull * 1024 * 4);
    float*  sel_f  = (float*)carve(4096ull * 1024 * 4);
    float*  proc_f = (float*)carve(4096ull * 1024 * 4);
    float*  scores = (float*)carve(8192ull * 4);
    int*    idx    = (int*)carve(4096ull * 4);
    float*  wsel   = (float*)carve(4096ull * 4);

    // ---- fp32 -> fp16 conversions (weights + initial x mirror) ----
    auto cvt = [&](const float* src, half_t* dst, size_t n) {
        const int n8 = (int)(n / 8);
        cvt_half8_kernel<<<(n8 + 255) / 256, 256, 0, stream>>>(src, dst, n8);
    };
    cvt(Wqkv, Wqkv_h, nWqkv);
    cvt(Wo, Wo_h, nWo);
    cvt(W1, W1_h, nW1);
    cvt(W2, W2_h, nW2);
    cvt(X, x_h, 8192ull * 1024);

    EncCtx c{bqkv, bo, b1, b2, g1, be1, g2, be2,
             Wqkv_h, Wo_h, W1_h, W2_h, qkv_h, o_h, h_h, vt, y_h, tmp_f, y_f};

    for (int layer = 0; layer < 6; layer++) {
        if (layer & 1) {
            // MoD: route top-1024 of 2048 tokens per sequence
            router_scores<<<2048, 256, 0, stream>>>(x, rw + layer * 1024, scores, 8192);
            topk_select<<<4, 256, 0, stream>>>(scores, idx, wsel);
            gather_kernel<<<4096, 256, 0, stream>>>(x, idx, sel_f, sel_h);
            // fp16 mirror of proc is unused; y_h is a safe dump target
            run_encoder(c, layer, sel_f, sel_h, proc_f, y_h, 4096, 1024, stream);
            scatter_kernel<<<4096, 256, 0, stream>>>(x, x_h, sel_f, proc_f, idx, wsel);
        } else {
            run_encoder(c, layer, x, x_h, x, x_h, 8192, 2048, stream);
        }
    }
}